// Round 2
// baseline (723.294 us; speedup 1.0000x reference)
//
#include <hip/hip_runtime.h>
#include <hip/hip_bf16.h>

// Strategy:
//   h = x @ W_node + b_node                (kernel 1, fp32 GEMM, LDS-staged W)
//   per-edge: out[row] += h[col]; agg[row] += edge_attr[e]; cnt[row] += 1
//                                          (kernel 2, wave-per-64-edge atomic scatter)
//   out[n] = (out[n] + agg[n]@W_edge + cnt*b_edge) / max(cnt,1)
//                                          (kernel 3, tiny GEMM + normalize)
// Key algebraic move: segment_sum(edge_attr @ W_edge + b_edge) =
//   segment_sum(edge_attr) @ W_edge + cnt * b_edge  -- 16x fewer GEMM FLOPs,
//   no 410 MB per-edge e materialization, only 32 extra atomics/edge.
//
// R1 fixes: edge_index is delivered as int32 by the harness (NOT int64 as in
// the JAX reference -- "integer -> const int*"); replaced hipMemsetAsync with
// a zeroing kernel to stay inside the graph-capture-safe API surface.

#define NG_ROWS 8

__global__ __launch_bounds__(256) void zero_k(float* __restrict__ p, int n4) {
  int i = blockIdx.x * blockDim.x + threadIdx.x;
  float4 z = make_float4(0.f, 0.f, 0.f, 0.f);
  for (; i < n4; i += gridDim.x * blockDim.x) ((float4*)p)[i] = z;
}

__global__ __launch_bounds__(256) void node_gemm_k(
    const float* __restrict__ x, const float* __restrict__ W,
    const float* __restrict__ b, float* __restrict__ h, int N) {
  __shared__ float wl[128 * 64];      // 32 KB
  __shared__ float xl[NG_ROWS * 128]; // 4 KB
  const int tid = threadIdx.x;
  // stage W (8192 floats) as float4, coalesced
  for (int i = tid; i < 128 * 64 / 4; i += 256)
    ((float4*)wl)[i] = ((const float4*)W)[i];
  const int r0 = blockIdx.x * NG_ROWS;
  // stage NG_ROWS rows of x (1024 floats = 256 float4)
  for (int i = tid; i < NG_ROWS * 128 / 4; i += 256) {
    int rr = i >> 5;          // row within block
    int kk = i & 31;          // float4 within row
    float4 v = make_float4(0.f, 0.f, 0.f, 0.f);
    if (r0 + rr < N) v = ((const float4*)(x + (size_t)(r0 + rr) * 128))[kk];
    ((float4*)xl)[i] = v;
  }
  __syncthreads();
  const int c = tid & 63;
  const int rg = tid >> 6;    // 0..3 -> each thread does 2 rows
  const float bias = b[c];
  float acc0 = bias, acc1 = bias;
  const float* x0 = &xl[(rg * 2) * 128];
  const float* x1 = &xl[(rg * 2 + 1) * 128];
#pragma unroll 8
  for (int k = 0; k < 128; ++k) {
    float w = wl[k * 64 + c];     // 64 consecutive floats: 2-way alias, free
    acc0 += x0[k] * w;            // wave-uniform broadcast reads
    acc1 += x1[k] * w;
  }
  const size_t r = (size_t)r0 + rg * 2;
  if (r < (size_t)N)     h[r * 64 + c] = acc0;
  if (r + 1 < (size_t)N) h[(r + 1) * 64 + c] = acc1;
}

__global__ __launch_bounds__(256) void edge_scatter_k(
    const int* __restrict__ ei, const float* __restrict__ attr,
    const float* __restrict__ h, float* __restrict__ s_out,
    float* __restrict__ agg, float* __restrict__ cnt, int E) {
  const int lane = threadIdx.x & 63;
  const int wave = blockIdx.x * (blockDim.x >> 6) + (threadIdx.x >> 6);
  const int base = wave * 64;
  if (base >= E) return;
  const int n = min(64, E - base);
  int row_l = 0, col_l = 0;
  if (lane < n) {               // coalesced 64x4B index loads, once per 64 edges
    row_l = ei[base + lane];
    col_l = ei[(size_t)E + base + lane];
  }
  for (int i = 0; i < n; ++i) {
    const int row = __shfl(row_l, i);
    const int col = __shfl(col_l, i);
    // gather h[col] (256B from L2/L3-resident 25.6MB table), scatter to out[row]
    const float v = h[(size_t)col * 64 + lane];
    atomicAdd(&s_out[(size_t)row * 64 + lane], v);
    if (lane < 32) {            // 128B coalesced streaming read of edge_attr
      const float a = attr[(size_t)(base + i) * 32 + lane];
      atomicAdd(&agg[(size_t)row * 32 + lane], a);
    }
    if (lane == 0) atomicAdd(&cnt[row], 1.0f);
  }
}

__global__ __launch_bounds__(256) void finalize_k(
    const float* __restrict__ agg, const float* __restrict__ cnt,
    const float* __restrict__ We, const float* __restrict__ be,
    float* __restrict__ out, int N) {
  __shared__ float wl[32 * 64];   // 8 KB
  __shared__ float al[4 * 32];
  const int tid = threadIdx.x;
  for (int i = tid; i < 32 * 64 / 4; i += 256)
    ((float4*)wl)[i] = ((const float4*)We)[i];
  const int r0 = blockIdx.x * 4;
  if (tid < 128) {
    int rr = tid >> 5, kk = tid & 31;
    al[tid] = (r0 + rr < N) ? agg[(size_t)(r0 + rr) * 32 + kk] : 0.f;
  }
  __syncthreads();
  const int c = tid & 63;
  const int rg = tid >> 6;
  const int r = r0 + rg;
  if (r >= N) return;
  const float cn = cnt[r];
  float acc = out[(size_t)r * 64 + c] + cn * be[c];
#pragma unroll
  for (int k = 0; k < 32; ++k)
    acc += al[rg * 32 + k] * wl[k * 64 + c];
  out[(size_t)r * 64 + c] = acc / fmaxf(cn, 1.0f);
}

extern "C" void kernel_launch(void* const* d_in, const int* in_sizes, int n_in,
                              void* d_out, int out_size, void* d_ws, size_t ws_size,
                              hipStream_t stream) {
  const float* x    = (const float*)d_in[0];
  const int*   ei   = (const int*)d_in[1];     // int32 per harness contract
  const float* attr = (const float*)d_in[2];
  const float* Wn   = (const float*)d_in[3];
  const float* bn   = (const float*)d_in[4];
  const float* We   = (const float*)d_in[5];
  const float* be   = (const float*)d_in[6];
  float* out = (float*)d_out;

  const int N = in_sizes[0] / 128;        // 100000
  const int E = in_sizes[2] / 32;         // 1600000

  float* h   = (float*)d_ws;              // N*64 f32 = 25.6 MB
  float* agg = h + (size_t)N * 64;        // N*32 f32 = 12.8 MB
  float* cnt = agg + (size_t)N * 32;      // N    f32 =  0.4 MB

  // zero accumulators (graph-capture-safe kernels, not hipMemsetAsync)
  zero_k<<<1024, 256, 0, stream>>>(out, N * 64 / 4);
  zero_k<<<1024, 256, 0, stream>>>(agg, N * 33 / 4);  // agg+cnt contiguous

  node_gemm_k<<<(N + NG_ROWS - 1) / NG_ROWS, 256, 0, stream>>>(x, Wn, bn, h, N);
  edge_scatter_k<<<(E + 255) / 256, 256, 0, stream>>>(ei, attr, h, out, agg, cnt, E);
  finalize_k<<<(N + 3) / 4, 256, 0, stream>>>(agg, cnt, We, be, out, N);
}

// Round 3
// 456.521 us; speedup vs baseline: 1.5844x; 1.5844x over previous
//
#include <hip/hip_runtime.h>
#include <hip/hip_bf16.h>

// R2 strategy: no fp32 atomics. Build CSR per call, pull-gather per node.
//   K0 zero deg
//   K1 hist:   deg[row]++                      (int atomics)
//   K2-4 scan: offs = exclusive_scan(deg)      (2-level, 1024/block)
//   K5 scatter: list[atomic(cursor[row])++] = (e<<32)|col  (CSR entries)
//   K6 node_gemm: h = x@W_node + b_node
//   K7 gather: per-node wave: acc += h[col]; acca += attr[e];
//              out = (acc + acca@W_edge + deg*b_edge)/max(deg,1)  -- one write
// Algebraic move retained: segment_sum(attr@We + be) = segment_sum(attr)@We
// + cnt*be, done per node in registers (32 shuffles), not per edge.

#define NG_ROWS 8
#define SCAN_E 1024

__global__ __launch_bounds__(256) void zero_k(float* __restrict__ p, int n4) {
  int i = blockIdx.x * blockDim.x + threadIdx.x;
  float4 z = make_float4(0.f, 0.f, 0.f, 0.f);
  for (; i < n4; i += gridDim.x * blockDim.x) ((float4*)p)[i] = z;
}

__global__ __launch_bounds__(256) void hist_k(const int* __restrict__ ei,
                                              int* __restrict__ deg, int E) {
  int e = blockIdx.x * blockDim.x + threadIdx.x;
  if (e < E) atomicAdd(&deg[ei[e]], 1);
}

__global__ __launch_bounds__(256) void scan1_k(const int* __restrict__ deg,
                                               int* __restrict__ offs,
                                               int* __restrict__ bsum, int N) {
  __shared__ int sd[256];
  const int t = threadIdx.x;
  const int e0 = blockIdx.x * SCAN_E + t * 4;
  int4 v = make_int4(0, 0, 0, 0);
  if (e0 + 3 < N) v = *(const int4*)(deg + e0);
  else {
    if (e0 + 0 < N) v.x = deg[e0 + 0];
    if (e0 + 1 < N) v.y = deg[e0 + 1];
    if (e0 + 2 < N) v.z = deg[e0 + 2];
    if (e0 + 3 < N) v.w = deg[e0 + 3];
  }
  const int s = v.x + v.y + v.z + v.w;
  sd[t] = s;
  __syncthreads();
  for (int off = 1; off < 256; off <<= 1) {
    int val = sd[t];
    int add = (t >= off) ? sd[t - off] : 0;
    __syncthreads();
    sd[t] = val + add;
    __syncthreads();
  }
  int o0 = sd[t] - s;  // exclusive
  if (t == 255) bsum[blockIdx.x] = sd[t];
  if (e0 + 0 < N) offs[e0 + 0] = o0; o0 += v.x;
  if (e0 + 1 < N) offs[e0 + 1] = o0; o0 += v.y;
  if (e0 + 2 < N) offs[e0 + 2] = o0; o0 += v.z;
  if (e0 + 3 < N) offs[e0 + 3] = o0;
}

__global__ __launch_bounds__(1024) void scan2_k(int* __restrict__ bsum, int nb) {
  __shared__ int sd[1024];
  const int t = threadIdx.x;
  const int v = (t < nb) ? bsum[t] : 0;
  sd[t] = v;
  __syncthreads();
  for (int off = 1; off < 1024; off <<= 1) {
    int val = sd[t];
    int add = (t >= off) ? sd[t - off] : 0;
    __syncthreads();
    sd[t] = val + add;
    __syncthreads();
  }
  if (t < nb) bsum[t] = sd[t] - v;  // exclusive, in place
}

__global__ __launch_bounds__(256) void scan3_k(int* __restrict__ offs,
                                               const int* __restrict__ bsum,
                                               int* __restrict__ cursor, int N) {
  int i = blockIdx.x * blockDim.x + threadIdx.x;
  if (i < N) {
    int o = offs[i] + bsum[i / SCAN_E];
    offs[i] = o;
    cursor[i] = o;
  }
}

__global__ __launch_bounds__(256) void scatter_k(const int* __restrict__ ei,
                                                 unsigned long long* __restrict__ list,
                                                 int* __restrict__ cursor, int E) {
  int e = blockIdx.x * blockDim.x + threadIdx.x;
  if (e < E) {
    const int row = ei[e];
    const unsigned int col = (unsigned int)ei[(size_t)E + e];
    const int pos = atomicAdd(&cursor[row], 1);
    list[pos] = ((unsigned long long)(unsigned int)e << 32) | col;
  }
}

__global__ __launch_bounds__(256) void node_gemm_k(
    const float* __restrict__ x, const float* __restrict__ W,
    const float* __restrict__ b, float* __restrict__ h, int N) {
  __shared__ float wl[128 * 64];      // 32 KB
  __shared__ float xl[NG_ROWS * 128]; // 4 KB
  const int tid = threadIdx.x;
  for (int i = tid; i < 128 * 64 / 4; i += 256)
    ((float4*)wl)[i] = ((const float4*)W)[i];
  const int r0 = blockIdx.x * NG_ROWS;
  for (int i = tid; i < NG_ROWS * 128 / 4; i += 256) {
    int rr = i >> 5, kk = i & 31;
    float4 v = make_float4(0.f, 0.f, 0.f, 0.f);
    if (r0 + rr < N) v = ((const float4*)(x + (size_t)(r0 + rr) * 128))[kk];
    ((float4*)xl)[i] = v;
  }
  __syncthreads();
  const int c = tid & 63;
  const int rg = tid >> 6;
  const float bias = b[c];
  float acc0 = bias, acc1 = bias;
  const float* x0 = &xl[(rg * 2) * 128];
  const float* x1 = &xl[(rg * 2 + 1) * 128];
#pragma unroll 8
  for (int k = 0; k < 128; ++k) {
    float w = wl[k * 64 + c];
    acc0 += x0[k] * w;
    acc1 += x1[k] * w;
  }
  const size_t r = (size_t)r0 + rg * 2;
  if (r < (size_t)N)     h[r * 64 + c] = acc0;
  if (r + 1 < (size_t)N) h[(r + 1) * 64 + c] = acc1;
}

__global__ __launch_bounds__(256) void gather_k(
    const unsigned long long* __restrict__ list, const int* __restrict__ offs,
    const int* __restrict__ cur, const float* __restrict__ h,
    const float* __restrict__ attr, const float* __restrict__ We,
    const float* __restrict__ be, float* __restrict__ out, int N) {
  __shared__ float wl[32 * 64];  // 8 KB W_edge
  for (int i = threadIdx.x; i < 32 * 64 / 4; i += 256)
    ((float4*)wl)[i] = ((const float4*)We)[i];
  __syncthreads();
  const int lane = threadIdx.x & 63;
  const int node = blockIdx.x * 4 + (threadIdx.x >> 6);
  if (node >= N) return;
  const int base = offs[node];
  const int deg = cur[node] - base;
  float acc = 0.f, acca = 0.f;
  for (int i0 = 0; i0 < deg; i0 += 64) {
    const int nn = min(64, deg - i0);
    unsigned long long ent = 0ull;
    if (lane < nn) ent = list[base + i0 + lane];  // coalesced 8B loads
    for (int j = 0; j < nn; ++j) {
      const unsigned long long e2 = __shfl(ent, j);
      const int col = (int)(e2 & 0xffffffffull);
      const int eid = (int)(e2 >> 32);
      acc += h[(size_t)col * 64 + lane];            // 256B wave gather, L2/L3
      if (lane < 32) acca += attr[(size_t)eid * 32 + lane];  // 128B half-wave
    }
  }
  // acca (channels in lanes 0..31) @ W_edge via broadcast
  float r = 0.f;
#pragma unroll
  for (int k = 0; k < 32; ++k)
    r += __shfl(acca, k) * wl[k * 64 + lane];
  const float cn = (float)deg;
  out[(size_t)node * 64 + lane] = (acc + r + cn * be[lane]) / fmaxf(cn, 1.0f);
}

extern "C" void kernel_launch(void* const* d_in, const int* in_sizes, int n_in,
                              void* d_out, int out_size, void* d_ws, size_t ws_size,
                              hipStream_t stream) {
  const float* x    = (const float*)d_in[0];
  const int*   ei   = (const int*)d_in[1];     // int32 per harness contract
  const float* attr = (const float*)d_in[2];
  const float* Wn   = (const float*)d_in[3];
  const float* bn   = (const float*)d_in[4];
  const float* We   = (const float*)d_in[5];
  const float* be   = (const float*)d_in[6];
  float* out = (float*)d_out;

  const int N = in_sizes[0] / 128;        // 100000
  const int E = in_sizes[2] / 32;         // 1600000

  // workspace layout (all 16B-aligned for N%4==0)
  float* h = (float*)d_ws;                                  // N*64 f32 = 25.6 MB
  unsigned long long* list = (unsigned long long*)(h + (size_t)N * 64);  // E*8B = 12.8 MB
  int* deg    = (int*)(list + (size_t)E);                   // N ints
  int* offs   = deg + N;                                    // N ints
  int* cursor = offs + N;                                   // N ints
  int* bsum   = cursor + N;                                 // <=1024 ints

  const int nb1 = (N + SCAN_E - 1) / SCAN_E;  // blocks in scan level 1 (<=1024)

  zero_k<<<128, 256, 0, stream>>>((float*)deg, (N + 3) / 4);
  hist_k<<<(E + 255) / 256, 256, 0, stream>>>(ei, deg, E);
  scan1_k<<<nb1, 256, 0, stream>>>(deg, offs, bsum, N);
  scan2_k<<<1, 1024, 0, stream>>>(bsum, nb1);
  scan3_k<<<(N + 255) / 256, 256, 0, stream>>>(offs, bsum, cursor, N);
  scatter_k<<<(E + 255) / 256, 256, 0, stream>>>(ei, list, cursor, E);
  node_gemm_k<<<(N + NG_ROWS - 1) / NG_ROWS, 256, 0, stream>>>(x, Wn, bn, h, N);
  gather_k<<<(N + 3) / 4, 256, 0, stream>>>(list, offs, cursor, h, attr, We, be, out, N);
}

// Round 4
// 365.561 us; speedup vs baseline: 1.9786x; 1.2488x over previous
//
#include <hip/hip_runtime.h>
#include <hip/hip_bf16.h>

// R3: CSR pull-gather, now with 8-wide ILP in the gather inner loop.
// Pipeline:
//   K0 zero deg; K1 hist deg[row]++; K2-4 exclusive scan -> offs;
//   K5 scatter list[cursor[row]++] = (eid<<32)|col;
//   K6 node_gemm h = x@W_node + b_node;
//   K7 gather per-node wave: acc += h[col]; acca += attr[eid] (8 edges per
//      batch, 16 loads in flight, clamped-index padding so the tail stays
//      parallel); out = (acc + acca@W_edge + deg*b_edge)/max(deg,1).

#define NG_ROWS 8
#define SCAN_E 1024

__global__ __launch_bounds__(256) void zero_k(float* __restrict__ p, int n4) {
  int i = blockIdx.x * blockDim.x + threadIdx.x;
  float4 z = make_float4(0.f, 0.f, 0.f, 0.f);
  for (; i < n4; i += gridDim.x * blockDim.x) ((float4*)p)[i] = z;
}

__global__ __launch_bounds__(256) void hist_k(const int* __restrict__ ei,
                                              int* __restrict__ deg, int E) {
  int e = blockIdx.x * blockDim.x + threadIdx.x;
  if (e < E) atomicAdd(&deg[ei[e]], 1);
}

__global__ __launch_bounds__(256) void scan1_k(const int* __restrict__ deg,
                                               int* __restrict__ offs,
                                               int* __restrict__ bsum, int N) {
  __shared__ int sd[256];
  const int t = threadIdx.x;
  const int e0 = blockIdx.x * SCAN_E + t * 4;
  int4 v = make_int4(0, 0, 0, 0);
  if (e0 + 3 < N) v = *(const int4*)(deg + e0);
  else {
    if (e0 + 0 < N) v.x = deg[e0 + 0];
    if (e0 + 1 < N) v.y = deg[e0 + 1];
    if (e0 + 2 < N) v.z = deg[e0 + 2];
    if (e0 + 3 < N) v.w = deg[e0 + 3];
  }
  const int s = v.x + v.y + v.z + v.w;
  sd[t] = s;
  __syncthreads();
  for (int off = 1; off < 256; off <<= 1) {
    int val = sd[t];
    int add = (t >= off) ? sd[t - off] : 0;
    __syncthreads();
    sd[t] = val + add;
    __syncthreads();
  }
  int o0 = sd[t] - s;  // exclusive
  if (t == 255) bsum[blockIdx.x] = sd[t];
  if (e0 + 0 < N) offs[e0 + 0] = o0; o0 += v.x;
  if (e0 + 1 < N) offs[e0 + 1] = o0; o0 += v.y;
  if (e0 + 2 < N) offs[e0 + 2] = o0; o0 += v.z;
  if (e0 + 3 < N) offs[e0 + 3] = o0;
}

__global__ __launch_bounds__(1024) void scan2_k(int* __restrict__ bsum, int nb) {
  __shared__ int sd[1024];
  const int t = threadIdx.x;
  const int v = (t < nb) ? bsum[t] : 0;
  sd[t] = v;
  __syncthreads();
  for (int off = 1; off < 1024; off <<= 1) {
    int val = sd[t];
    int add = (t >= off) ? sd[t - off] : 0;
    __syncthreads();
    sd[t] = val + add;
    __syncthreads();
  }
  if (t < nb) bsum[t] = sd[t] - v;  // exclusive, in place
}

__global__ __launch_bounds__(256) void scan3_k(int* __restrict__ offs,
                                               const int* __restrict__ bsum,
                                               int* __restrict__ cursor, int N) {
  int i = blockIdx.x * blockDim.x + threadIdx.x;
  if (i < N) {
    int o = offs[i] + bsum[i / SCAN_E];
    offs[i] = o;
    cursor[i] = o;
  }
}

__global__ __launch_bounds__(256) void scatter_k(const int* __restrict__ ei,
                                                 unsigned long long* __restrict__ list,
                                                 int* __restrict__ cursor, int E) {
  int e = blockIdx.x * blockDim.x + threadIdx.x;
  if (e < E) {
    const int row = ei[e];
    const unsigned int col = (unsigned int)ei[(size_t)E + e];
    const int pos = atomicAdd(&cursor[row], 1);
    list[pos] = ((unsigned long long)(unsigned int)e << 32) | col;
  }
}

__global__ __launch_bounds__(256) void node_gemm_k(
    const float* __restrict__ x, const float* __restrict__ W,
    const float* __restrict__ b, float* __restrict__ h, int N) {
  __shared__ float wl[128 * 64];      // 32 KB
  __shared__ float xl[NG_ROWS * 128]; // 4 KB
  const int tid = threadIdx.x;
  for (int i = tid; i < 128 * 64 / 4; i += 256)
    ((float4*)wl)[i] = ((const float4*)W)[i];
  const int r0 = blockIdx.x * NG_ROWS;
  for (int i = tid; i < NG_ROWS * 128 / 4; i += 256) {
    int rr = i >> 5, kk = i & 31;
    float4 v = make_float4(0.f, 0.f, 0.f, 0.f);
    if (r0 + rr < N) v = ((const float4*)(x + (size_t)(r0 + rr) * 128))[kk];
    ((float4*)xl)[i] = v;
  }
  __syncthreads();
  const int c = tid & 63;
  const int rg = tid >> 6;
  const float bias = b[c];
  float acc0 = bias, acc1 = bias;
  const float* x0 = &xl[(rg * 2) * 128];
  const float* x1 = &xl[(rg * 2 + 1) * 128];
#pragma unroll 8
  for (int k = 0; k < 128; ++k) {
    float w = wl[k * 64 + c];   // stride-1 across lanes: 2-way alias, free
    acc0 += x0[k] * w;          // wave-uniform broadcast reads
    acc1 += x1[k] * w;
  }
  const size_t r = (size_t)r0 + rg * 2;
  if (r < (size_t)N)     h[r * 64 + c] = acc0;
  if (r + 1 < (size_t)N) h[(r + 1) * 64 + c] = acc1;
}

__global__ __launch_bounds__(256) void gather_k(
    const unsigned long long* __restrict__ list, const int* __restrict__ offs,
    const int* __restrict__ degv, const float* __restrict__ h,
    const float* __restrict__ attr, const float* __restrict__ We,
    const float* __restrict__ be, float* __restrict__ out, int N) {
  __shared__ float wl[32 * 64];  // 8 KB W_edge
  for (int i = threadIdx.x; i < 32 * 64 / 4; i += 256)
    ((float4*)wl)[i] = ((const float4*)We)[i];
  __syncthreads();
  const int lane = threadIdx.x & 63;
  const int node = blockIdx.x * 4 + (threadIdx.x >> 6);
  if (node >= N) return;
  const int base = offs[node];
  const int deg = degv[node];
  float acc = 0.f, acca = 0.f;
  for (int i0 = 0; i0 < deg; i0 += 64) {
    const int nn = min(64, deg - i0);
    unsigned long long ent = 0ull;
    if (lane < nn) ent = list[base + i0 + lane];  // coalesced 8B loads
    // 8 edges per batch: issue all 16 loads before accumulating (ILP).
    // Out-of-range u clamps to entry nn-1 (always valid; deg>0 here) and is
    // dropped by a wave-uniform predicate, so the tail never serializes.
    for (int j = 0; j < nn; j += 8) {
      float v[8], a[8];
#pragma unroll
      for (int u = 0; u < 8; ++u) {
        const int jj = (j + u < nn) ? (j + u) : (nn - 1);
        const unsigned long long e2 = __shfl(ent, jj);
        const int col = (int)(e2 & 0xffffffffull);
        const int eid = (int)(e2 >> 32);
        v[u] = h[(size_t)col * 64 + lane];
        a[u] = (lane < 32) ? attr[(size_t)eid * 32 + lane] : 0.f;
      }
#pragma unroll
      for (int u = 0; u < 8; ++u) {
        if (j + u < nn) { acc += v[u]; acca += a[u]; }  // uniform predicate
      }
    }
  }
  // acca (channels in lanes 0..31) @ W_edge via broadcast
  float r = 0.f;
#pragma unroll
  for (int k = 0; k < 32; ++k)
    r += __shfl(acca, k) * wl[k * 64 + lane];
  const float cn = (float)deg;
  out[(size_t)node * 64 + lane] = (acc + r + cn * be[lane]) / fmaxf(cn, 1.0f);
}

extern "C" void kernel_launch(void* const* d_in, const int* in_sizes, int n_in,
                              void* d_out, int out_size, void* d_ws, size_t ws_size,
                              hipStream_t stream) {
  const float* x    = (const float*)d_in[0];
  const int*   ei   = (const int*)d_in[1];     // int32 per harness contract
  const float* attr = (const float*)d_in[2];
  const float* Wn   = (const float*)d_in[3];
  const float* bn   = (const float*)d_in[4];
  const float* We   = (const float*)d_in[5];
  const float* be   = (const float*)d_in[6];
  float* out = (float*)d_out;

  const int N = in_sizes[0] / 128;        // 100000
  const int E = in_sizes[2] / 32;         // 1600000

  // workspace layout (16B-aligned; N%4==0)
  float* h = (float*)d_ws;                                  // N*64 f32
  unsigned long long* list = (unsigned long long*)(h + (size_t)N * 64);  // E*8B
  int* deg    = (int*)(list + (size_t)E);                   // N ints
  int* offs   = deg + N;                                    // N ints
  int* cursor = offs + N;                                   // N ints
  int* bsum   = cursor + N;                                 // <=1024 ints

  const int nb1 = (N + SCAN_E - 1) / SCAN_E;

  zero_k<<<128, 256, 0, stream>>>((float*)deg, (N + 3) / 4);
  hist_k<<<(E + 255) / 256, 256, 0, stream>>>(ei, deg, E);
  scan1_k<<<nb1, 256, 0, stream>>>(deg, offs, bsum, N);
  scan2_k<<<1, 1024, 0, stream>>>(bsum, nb1);
  scan3_k<<<(N + 255) / 256, 256, 0, stream>>>(offs, bsum, cursor, N);
  scatter_k<<<(E + 255) / 256, 256, 0, stream>>>(ei, list, cursor, E);
  node_gemm_k<<<(N + NG_ROWS - 1) / NG_ROWS, 256, 0, stream>>>(x, Wn, bn, h, N);
  gather_k<<<(N + 3) / 4, 256, 0, stream>>>(list, offs, deg, h, attr, We, be, out, N);
}

// Round 8
// 322.373 us; speedup vs baseline: 2.2437x; 1.1340x over previous
//
#include <hip/hip_runtime.h>
#include <hip/hip_bf16.h>

// R5 (3rd resubmit; R5/R6/R7 benches were infra failures -- container
// refused connection before the first message, same signature as round 0's
// stub run): CSR built via two-phase bucketed partition (no random 8B
// scatters, no per-row global atomics in the hot path).
//   K0 zero deg; K1 hist deg[row]++; K2-4 exclusive scan -> offs (+bcur);
//   K5 part1: partition edges into buckets of 256 rows; per-block LDS hist,
//      one global atomic per (block,bucket) run reservation; packed 46-bit
//      entries (rowlocal|eid|col) written to per-block contiguous runs.
//   K6 part2: one block per bucket; LDS row cursors; stream temp slice ->
//      exact CSR positions in `list` (writes confined to ~32KB L2 slice).
//   K7 node_gemm h = x@W_node + b_node  (temp aliased h, dead by now)
//   K8 gather per-node wave, 8-edge ILP groups, paired full-wave attr loads;
//      out = (acc + acca@W_edge + deg*b_edge)/max(deg,1).

#define NG_ROWS 8
#define SCAN_E 1024
#define EPB 8192            // edges per part1 block
#define NBMAX 512           // max buckets (N <= 131072)

__global__ __launch_bounds__(256) void zero_k(float* __restrict__ p, int n4) {
  int i = blockIdx.x * blockDim.x + threadIdx.x;
  float4 z = make_float4(0.f, 0.f, 0.f, 0.f);
  for (; i < n4; i += gridDim.x * blockDim.x) ((float4*)p)[i] = z;
}

__global__ __launch_bounds__(256) void hist_k(const int* __restrict__ ei,
                                              int* __restrict__ deg, int E) {
  int e = blockIdx.x * blockDim.x + threadIdx.x;
  if (e < E) atomicAdd(&deg[ei[e]], 1);
}

__global__ __launch_bounds__(256) void scan1_k(const int* __restrict__ deg,
                                               int* __restrict__ offs,
                                               int* __restrict__ bsum, int N) {
  __shared__ int sd[256];
  const int t = threadIdx.x;
  const int e0 = blockIdx.x * SCAN_E + t * 4;
  int4 v = make_int4(0, 0, 0, 0);
  if (e0 + 3 < N) v = *(const int4*)(deg + e0);
  else {
    if (e0 + 0 < N) v.x = deg[e0 + 0];
    if (e0 + 1 < N) v.y = deg[e0 + 1];
    if (e0 + 2 < N) v.z = deg[e0 + 2];
    if (e0 + 3 < N) v.w = deg[e0 + 3];
  }
  const int s = v.x + v.y + v.z + v.w;
  sd[t] = s;
  __syncthreads();
  for (int off = 1; off < 256; off <<= 1) {
    int val = sd[t];
    int add = (t >= off) ? sd[t - off] : 0;
    __syncthreads();
    sd[t] = val + add;
    __syncthreads();
  }
  int o0 = sd[t] - s;  // exclusive
  if (t == 255) bsum[blockIdx.x] = sd[t];
  if (e0 + 0 < N) offs[e0 + 0] = o0; o0 += v.x;
  if (e0 + 1 < N) offs[e0 + 1] = o0; o0 += v.y;
  if (e0 + 2 < N) offs[e0 + 2] = o0; o0 += v.z;
  if (e0 + 3 < N) offs[e0 + 3] = o0;
}

__global__ __launch_bounds__(1024) void scan2_k(int* __restrict__ bsum, int nb) {
  __shared__ int sd[1024];
  const int t = threadIdx.x;
  const int v = (t < nb) ? bsum[t] : 0;
  sd[t] = v;
  __syncthreads();
  for (int off = 1; off < 1024; off <<= 1) {
    int val = sd[t];
    int add = (t >= off) ? sd[t - off] : 0;
    __syncthreads();
    sd[t] = val + add;
    __syncthreads();
  }
  if (t < nb) bsum[t] = sd[t] - v;  // exclusive, in place
}

__global__ __launch_bounds__(256) void scan3_k(int* __restrict__ offs,
                                               const int* __restrict__ bsum,
                                               int* __restrict__ bcur, int N) {
  int i = blockIdx.x * blockDim.x + threadIdx.x;
  if (i < N) {
    int o = offs[i] + bsum[i / SCAN_E];
    offs[i] = o;
    if ((i & 255) == 0) bcur[i >> 8] = o;  // bucket write cursor = offs[b*256]
  }
}

// Partition edges into buckets of 256 rows. Entry: rowlocal<<38 | eid<<17 | col
// (needs N < 2^17=131072, E < 2^21=2097152).
__global__ __launch_bounds__(256) void part1_k(
    const int* __restrict__ ei, unsigned long long* __restrict__ temp,
    int* __restrict__ bcur, int E, int NB) {
  __shared__ int hist[NBMAX];
  __shared__ int base[NBMAX];
  const int t = threadIdx.x;
  for (int i = t; i < NB; i += 256) hist[i] = 0;
  __syncthreads();
  const int e0 = blockIdx.x * EPB;
#pragma unroll 4
  for (int i = 0; i < EPB / 256; ++i) {
    const int e = e0 + i * 256 + t;
    if (e < E) atomicAdd(&hist[ei[e] >> 8], 1);
  }
  __syncthreads();
  for (int i = t; i < NB; i += 256) {
    const int c = hist[i];
    base[i] = c ? atomicAdd(&bcur[i], c) : 0;
    hist[i] = 0;  // reuse as run cursor
  }
  __syncthreads();
#pragma unroll 4
  for (int i = 0; i < EPB / 256; ++i) {
    const int e = e0 + i * 256 + t;
    if (e >= E) continue;
    const int row = ei[e];
    const unsigned long long col = (unsigned long long)(unsigned int)ei[(size_t)E + e];
    const int b = row >> 8;
    const int pos = base[b] + atomicAdd(&hist[b], 1);
    temp[pos] = ((unsigned long long)(row & 255) << 38) |
                ((unsigned long long)(unsigned int)e << 17) | col;
  }
}

// One block per bucket: LDS row cursors, temp slice -> exact CSR positions.
__global__ __launch_bounds__(256) void part2_k(
    const unsigned long long* __restrict__ temp, const int* __restrict__ offs,
    unsigned long long* __restrict__ list, int E, int N, int NB) {
  __shared__ int lcur[256];
  const int b = blockIdx.x;
  const int t = threadIdx.x;
  const int r0 = b << 8;
  lcur[t] = (r0 + t < N) ? offs[r0 + t] : 0;
  __syncthreads();
  const int start = lcur[0];
  const int end = (b == NB - 1) ? E : offs[r0 + 256];
  for (int i = start + t; i < end; i += 256) {
    const unsigned long long ent = temp[i];
    const int rl = (int)(ent >> 38);
    const int pos = atomicAdd(&lcur[rl], 1);  // LDS atomic, block-private
    list[pos] = ent;
  }
}

__global__ __launch_bounds__(256) void node_gemm_k(
    const float* __restrict__ x, const float* __restrict__ W,
    const float* __restrict__ b, float* __restrict__ h, int N) {
  __shared__ float wl[128 * 64];      // 32 KB
  __shared__ float xl[NG_ROWS * 128]; // 4 KB
  const int tid = threadIdx.x;
  for (int i = tid; i < 128 * 64 / 4; i += 256)
    ((float4*)wl)[i] = ((const float4*)W)[i];
  const int r0 = blockIdx.x * NG_ROWS;
  for (int i = tid; i < NG_ROWS * 128 / 4; i += 256) {
    int rr = i >> 5, kk = i & 31;
    float4 v = make_float4(0.f, 0.f, 0.f, 0.f);
    if (r0 + rr < N) v = ((const float4*)(x + (size_t)(r0 + rr) * 128))[kk];
    ((float4*)xl)[i] = v;
  }
  __syncthreads();
  const int c = tid & 63;
  const int rg = tid >> 6;
  const float bias = b[c];
  float acc0 = bias, acc1 = bias;
  const float* x0 = &xl[(rg * 2) * 128];
  const float* x1 = &xl[(rg * 2 + 1) * 128];
#pragma unroll 8
  for (int k = 0; k < 128; ++k) {
    float w = wl[k * 64 + c];   // stride-1 across lanes: 2-way alias, free
    acc0 += x0[k] * w;          // wave-uniform broadcast reads
    acc1 += x1[k] * w;
  }
  const size_t r = (size_t)r0 + rg * 2;
  if (r < (size_t)N)     h[r * 64 + c] = acc0;
  if (r + 1 < (size_t)N) h[(r + 1) * 64 + c] = acc1;
}

__global__ __launch_bounds__(256) void gather_k(
    const unsigned long long* __restrict__ list, const int* __restrict__ offs,
    const int* __restrict__ degv, const float* __restrict__ h,
    const float* __restrict__ attr, const float* __restrict__ We,
    const float* __restrict__ be, float* __restrict__ out, int N) {
  __shared__ float wl[32 * 64];  // 8 KB W_edge
  for (int i = threadIdx.x; i < 32 * 64 / 4; i += 256)
    ((float4*)wl)[i] = ((const float4*)We)[i];
  __syncthreads();
  const int lane = threadIdx.x & 63;
  const int node = blockIdx.x * 4 + (threadIdx.x >> 6);
  if (node >= N) return;
  const int base = offs[node];
  const int deg = degv[node];
  float acc = 0.f, acca = 0.f;
  for (int i0 = 0; i0 < deg; i0 += 64) {
    const int nn = min(64, deg - i0);
    unsigned long long ent = 0ull;
    if (lane < nn) ent = list[base + i0 + lane];  // coalesced 8B loads
    // 8 edges per group: issue all loads before accumulating. attr rows are
    // paired: lanes 0-31 read edge 2q, lanes 32-63 read edge 2q+1 (full-wave
    // loads, half the attr VMEM instrs). Tail pads via clamped index + drop.
    for (int j = 0; j < nn; j += 8) {
      float v[8], a[4];
#pragma unroll
      for (int u = 0; u < 8; ++u) {
        const int jj = (j + u < nn) ? (j + u) : (nn - 1);
        const unsigned long long e2 = __shfl(ent, jj);
        const int col = (int)(e2 & 0x1FFFFull);
        v[u] = h[(size_t)col * 64 + lane];
      }
#pragma unroll
      for (int q = 0; q < 4; ++q) {
        const int ju = j + 2 * q + (lane >> 5);
        const int jj = (ju < nn) ? ju : (nn - 1);
        const unsigned long long e2 = __shfl(ent, jj);
        const int eid = (int)((e2 >> 17) & 0x1FFFFFull);
        a[q] = attr[(size_t)eid * 32 + (lane & 31)];
      }
#pragma unroll
      for (int u = 0; u < 8; ++u)
        if (j + u < nn) acc += v[u];
#pragma unroll
      for (int q = 0; q < 4; ++q)
        if (j + 2 * q + (lane >> 5) < nn) acca += a[q];
    }
  }
  // acca channels live split across lane halves; combine in the @W_edge reduce
  float r = 0.f;
#pragma unroll
  for (int k = 0; k < 32; ++k)
    r += (__shfl(acca, k) + __shfl(acca, k + 32)) * wl[k * 64 + lane];
  const float cn = (float)deg;
  out[(size_t)node * 64 + lane] = (acc + r + cn * be[lane]) / fmaxf(cn, 1.0f);
}

extern "C" void kernel_launch(void* const* d_in, const int* in_sizes, int n_in,
                              void* d_out, int out_size, void* d_ws, size_t ws_size,
                              hipStream_t stream) {
  const float* x    = (const float*)d_in[0];
  const int*   ei   = (const int*)d_in[1];     // int32 per harness contract
  const float* attr = (const float*)d_in[2];
  const float* Wn   = (const float*)d_in[3];
  const float* bn   = (const float*)d_in[4];
  const float* We   = (const float*)d_in[5];
  const float* be   = (const float*)d_in[6];
  float* out = (float*)d_out;

  const int N = in_sizes[0] / 128;        // 100000
  const int E = in_sizes[2] / 32;         // 1600000
  const int NB = (N + 255) >> 8;          // 391 buckets of 256 rows

  // workspace: temp aliases h (partition finishes before node_gemm runs)
  float* h = (float*)d_ws;                                  // N*64 f32 (25.6 MB)
  unsigned long long* temp = (unsigned long long*)d_ws;     // E*8B <= h region
  unsigned long long* list = (unsigned long long*)(h + (size_t)N * 64);  // E*8B
  int* deg  = (int*)(list + (size_t)E);                     // N ints
  int* offs = deg + N;                                      // N ints
  int* bcur = offs + N;                                     // NBMAX ints
  int* bsum = bcur + NBMAX;                                 // <=1024 ints

  const int nb1 = (N + SCAN_E - 1) / SCAN_E;

  zero_k<<<128, 256, 0, stream>>>((float*)deg, (N + 3) / 4);
  hist_k<<<(E + 255) / 256, 256, 0, stream>>>(ei, deg, E);
  scan1_k<<<nb1, 256, 0, stream>>>(deg, offs, bsum, N);
  scan2_k<<<1, 1024, 0, stream>>>(bsum, nb1);
  scan3_k<<<(N + 255) / 256, 256, 0, stream>>>(offs, bsum, bcur, N);
  part1_k<<<(E + EPB - 1) / EPB, 256, 0, stream>>>(ei, temp, bcur, E, NB);
  part2_k<<<NB, 256, 0, stream>>>(temp, offs, list, E, N, NB);
  node_gemm_k<<<(N + NG_ROWS - 1) / NG_ROWS, 256, 0, stream>>>(x, Wn, bn, h, N);
  gather_k<<<(N + 3) / 4, 256, 0, stream>>>(list, offs, deg, h, attr, We, be, out, N);
}

// Round 9
// 304.624 us; speedup vs baseline: 2.3744x; 1.0583x over previous
//
#include <hip/hip_runtime.h>
#include <hip/hip_bf16.h>

// R9: scalarized gather. CSR entries are wave-uniform -> readfirstlane them
// and do all col/eid extraction + address math on the SALU; h/attr loads are
// saddr-form with a per-lane byte offset. Zero DS ops, ~4 VALU per edge
// (2 readfirstlane + 2 fma). Tail via uniform clamp + 0/1 scale fma.
// node_gemm: x rows are wave-uniform -> scalar/broadcast global float4 loads
// (no xl LDS staging); W stays in LDS. 4 DS + 8 FMA per 4k (was 12:8).
// Partition pipeline (R5) unchanged: zero/hist/scan/part1/part2.

#define NG_ROWS 8
#define SCAN_E 1024
#define EPB 8192            // edges per part1 block
#define NBMAX 512           // max buckets (N <= 131072)

__global__ __launch_bounds__(256) void zero_k(float* __restrict__ p, int n4) {
  int i = blockIdx.x * blockDim.x + threadIdx.x;
  float4 z = make_float4(0.f, 0.f, 0.f, 0.f);
  for (; i < n4; i += gridDim.x * blockDim.x) ((float4*)p)[i] = z;
}

__global__ __launch_bounds__(256) void hist_k(const int* __restrict__ ei,
                                              int* __restrict__ deg, int E) {
  int e = blockIdx.x * blockDim.x + threadIdx.x;
  if (e < E) atomicAdd(&deg[ei[e]], 1);
}

__global__ __launch_bounds__(256) void scan1_k(const int* __restrict__ deg,
                                               int* __restrict__ offs,
                                               int* __restrict__ bsum, int N) {
  __shared__ int sd[256];
  const int t = threadIdx.x;
  const int e0 = blockIdx.x * SCAN_E + t * 4;
  int4 v = make_int4(0, 0, 0, 0);
  if (e0 + 3 < N) v = *(const int4*)(deg + e0);
  else {
    if (e0 + 0 < N) v.x = deg[e0 + 0];
    if (e0 + 1 < N) v.y = deg[e0 + 1];
    if (e0 + 2 < N) v.z = deg[e0 + 2];
    if (e0 + 3 < N) v.w = deg[e0 + 3];
  }
  const int s = v.x + v.y + v.z + v.w;
  sd[t] = s;
  __syncthreads();
  for (int off = 1; off < 256; off <<= 1) {
    int val = sd[t];
    int add = (t >= off) ? sd[t - off] : 0;
    __syncthreads();
    sd[t] = val + add;
    __syncthreads();
  }
  int o0 = sd[t] - s;  // exclusive
  if (t == 255) bsum[blockIdx.x] = sd[t];
  if (e0 + 0 < N) offs[e0 + 0] = o0; o0 += v.x;
  if (e0 + 1 < N) offs[e0 + 1] = o0; o0 += v.y;
  if (e0 + 2 < N) offs[e0 + 2] = o0; o0 += v.z;
  if (e0 + 3 < N) offs[e0 + 3] = o0;
}

__global__ __launch_bounds__(1024) void scan2_k(int* __restrict__ bsum, int nb) {
  __shared__ int sd[1024];
  const int t = threadIdx.x;
  const int v = (t < nb) ? bsum[t] : 0;
  sd[t] = v;
  __syncthreads();
  for (int off = 1; off < 1024; off <<= 1) {
    int val = sd[t];
    int add = (t >= off) ? sd[t - off] : 0;
    __syncthreads();
    sd[t] = val + add;
    __syncthreads();
  }
  if (t < nb) bsum[t] = sd[t] - v;  // exclusive, in place
}

__global__ __launch_bounds__(256) void scan3_k(int* __restrict__ offs,
                                               const int* __restrict__ bsum,
                                               int* __restrict__ bcur, int N) {
  int i = blockIdx.x * blockDim.x + threadIdx.x;
  if (i < N) {
    int o = offs[i] + bsum[i / SCAN_E];
    offs[i] = o;
    if ((i & 255) == 0) bcur[i >> 8] = o;  // bucket write cursor = offs[b*256]
  }
}

// Partition edges into buckets of 256 rows. Entry: rowlocal<<38 | eid<<17 | col
// (needs N < 2^17=131072, E < 2^21=2097152).
__global__ __launch_bounds__(256) void part1_k(
    const int* __restrict__ ei, unsigned long long* __restrict__ temp,
    int* __restrict__ bcur, int E, int NB) {
  __shared__ int hist[NBMAX];
  __shared__ int base[NBMAX];
  const int t = threadIdx.x;
  for (int i = t; i < NB; i += 256) hist[i] = 0;
  __syncthreads();
  const int e0 = blockIdx.x * EPB;
#pragma unroll 4
  for (int i = 0; i < EPB / 256; ++i) {
    const int e = e0 + i * 256 + t;
    if (e < E) atomicAdd(&hist[ei[e] >> 8], 1);
  }
  __syncthreads();
  for (int i = t; i < NB; i += 256) {
    const int c = hist[i];
    base[i] = c ? atomicAdd(&bcur[i], c) : 0;
    hist[i] = 0;  // reuse as run cursor
  }
  __syncthreads();
#pragma unroll 4
  for (int i = 0; i < EPB / 256; ++i) {
    const int e = e0 + i * 256 + t;
    if (e >= E) continue;
    const int row = ei[e];
    const unsigned long long col = (unsigned long long)(unsigned int)ei[(size_t)E + e];
    const int b = row >> 8;
    const int pos = base[b] + atomicAdd(&hist[b], 1);
    temp[pos] = ((unsigned long long)(row & 255) << 38) |
                ((unsigned long long)(unsigned int)e << 17) | col;
  }
}

// One block per bucket: LDS row cursors, temp slice -> exact CSR positions.
__global__ __launch_bounds__(256) void part2_k(
    const unsigned long long* __restrict__ temp, const int* __restrict__ offs,
    unsigned long long* __restrict__ list, int E, int N, int NB) {
  __shared__ int lcur[256];
  const int b = blockIdx.x;
  const int t = threadIdx.x;
  const int r0 = b << 8;
  lcur[t] = (r0 + t < N) ? offs[r0 + t] : 0;
  __syncthreads();
  const int start = lcur[0];
  const int end = (b == NB - 1) ? E : offs[r0 + 256];
  for (int i = start + t; i < end; i += 256) {
    const unsigned long long ent = temp[i];
    const int rl = (int)(ent >> 38);
    const int pos = atomicAdd(&lcur[rl], 1);  // LDS atomic, block-private
    list[pos] = ent;
  }
}

__global__ __launch_bounds__(256) void node_gemm_k(
    const float* __restrict__ x, const float* __restrict__ W,
    const float* __restrict__ b, float* __restrict__ h, int N) {
  __shared__ float wl[128 * 64];      // 32 KB, W[k][c]
  const int tid = threadIdx.x;
  for (int i = tid; i < 128 * 64 / 4; i += 256)
    ((float4*)wl)[i] = ((const float4*)W)[i];
  __syncthreads();
  const int c = tid & 63;
  const int rg = tid >> 6;            // wave 0..3, 2 rows each
  const int row = __builtin_amdgcn_readfirstlane(blockIdx.x * NG_ROWS + rg * 2);
  if (row >= N) return;               // uniform
  const bool has1 = (row + 1 < N);
  const float* xa = x + (size_t)row * 128;
  const float* xb = xa + (has1 ? 128 : 0);  // safe dup when tail
  const float bias = b[c];
  float acc0 = bias, acc1 = bias;
  // x rows are wave-uniform -> scalar/broadcast float4 loads, no LDS staging.
#pragma unroll 8
  for (int k = 0; k < 128; k += 4) {
    const float4 xa4 = *(const float4*)(xa + k);
    const float4 xb4 = *(const float4*)(xb + k);
    const float w0 = wl[(k + 0) * 64 + c];
    const float w1 = wl[(k + 1) * 64 + c];
    const float w2 = wl[(k + 2) * 64 + c];
    const float w3 = wl[(k + 3) * 64 + c];
    acc0 = fmaf(xa4.x, w0, acc0); acc1 = fmaf(xb4.x, w0, acc1);
    acc0 = fmaf(xa4.y, w1, acc0); acc1 = fmaf(xb4.y, w1, acc1);
    acc0 = fmaf(xa4.z, w2, acc0); acc1 = fmaf(xb4.z, w2, acc1);
    acc0 = fmaf(xa4.w, w3, acc0); acc1 = fmaf(xb4.w, w3, acc1);
  }
  h[(size_t)row * 64 + c] = acc0;
  if (has1) h[(size_t)(row + 1) * 64 + c] = acc1;
}

__global__ __launch_bounds__(256) void gather_k(
    const unsigned long long* __restrict__ list, const int* __restrict__ offs,
    const int* __restrict__ degv, const float* __restrict__ h,
    const float* __restrict__ attr, const float* __restrict__ We,
    const float* __restrict__ be, float* __restrict__ out, int N) {
  __shared__ float wl[32 * 64];  // 8 KB W_edge
  for (int i = threadIdx.x; i < 32 * 64 / 4; i += 256)
    ((float4*)wl)[i] = ((const float4*)We)[i];
  __syncthreads();
  const int lane = threadIdx.x & 63;
  const int node = blockIdx.x * 4 + (threadIdx.x >> 6);
  if (node >= N) return;
  // wave-uniform scalars: everything downstream runs on the SALU
  const int base = __builtin_amdgcn_readfirstlane(offs[node]);
  const int deg  = __builtin_amdgcn_readfirstlane(degv[node]);
  float acc = 0.f, acca = 0.f;
  for (int j = 0; j < deg; j += 8) {
    float v[8], a[8];
#pragma unroll
    for (int u = 0; u < 8; ++u) {
      int jj = j + u; jj = (jj < deg) ? jj : (deg - 1);   // uniform clamp
      const unsigned long long e2 = list[base + jj];       // uniform 8B load
      const int lo = __builtin_amdgcn_readfirstlane((int)(unsigned int)e2);
      const int hi = __builtin_amdgcn_readfirstlane((int)(unsigned int)(e2 >> 32));
      // entry: rl<<38 | eid<<17 | col  (scalar extraction)
      const int col = lo & 0x1FFFF;
      const int eid = ((unsigned int)lo >> 17) | ((hi & 0x3F) << 15);
      v[u] = h[(size_t)col * 64 + lane];               // saddr + lane*4
      a[u] = attr[(size_t)eid * 32 + (lane & 31)];     // dup halves -> 1x128B
    }
#pragma unroll
    for (int u = 0; u < 8; ++u) {
      const float sc = (j + u < deg) ? 1.0f : 0.0f;    // uniform 0/1
      acc  = fmaf(v[u], sc, acc);
      acca = fmaf(a[u], sc, acca);
    }
  }
  // acca (channel k in lane k, duplicated in lanes k+32) @ W_edge
  float r = 0.f;
#pragma unroll
  for (int k = 0; k < 32; ++k)
    r += __shfl(acca, k) * wl[k * 64 + lane];
  const float cn = (float)deg;
  out[(size_t)node * 64 + lane] = (acc + r + cn * be[lane]) / fmaxf(cn, 1.0f);
}

extern "C" void kernel_launch(void* const* d_in, const int* in_sizes, int n_in,
                              void* d_out, int out_size, void* d_ws, size_t ws_size,
                              hipStream_t stream) {
  const float* x    = (const float*)d_in[0];
  const int*   ei   = (const int*)d_in[1];     // int32 per harness contract
  const float* attr = (const float*)d_in[2];
  const float* Wn   = (const float*)d_in[3];
  const float* bn   = (const float*)d_in[4];
  const float* We   = (const float*)d_in[5];
  const float* be   = (const float*)d_in[6];
  float* out = (float*)d_out;

  const int N = in_sizes[0] / 128;        // 100000
  const int E = in_sizes[2] / 32;         // 1600000
  const int NB = (N + 255) >> 8;          // 391 buckets of 256 rows

  // workspace: temp aliases h (partition finishes before node_gemm runs)
  float* h = (float*)d_ws;                                  // N*64 f32 (25.6 MB)
  unsigned long long* temp = (unsigned long long*)d_ws;     // E*8B <= h region
  unsigned long long* list = (unsigned long long*)(h + (size_t)N * 64);  // E*8B
  int* deg  = (int*)(list + (size_t)E);                     // N ints
  int* offs = deg + N;                                      // N ints
  int* bcur = offs + N;                                     // NBMAX ints
  int* bsum = bcur + NBMAX;                                 // <=1024 ints

  const int nb1 = (N + SCAN_E - 1) / SCAN_E;

  zero_k<<<128, 256, 0, stream>>>((float*)deg, (N + 3) / 4);
  hist_k<<<(E + 255) / 256, 256, 0, stream>>>(ei, deg, E);
  scan1_k<<<nb1, 256, 0, stream>>>(deg, offs, bsum, N);
  scan2_k<<<1, 1024, 0, stream>>>(bsum, nb1);
  scan3_k<<<(N + 255) / 256, 256, 0, stream>>>(offs, bsum, bcur, N);
  part1_k<<<(E + EPB - 1) / EPB, 256, 0, stream>>>(ei, temp, bcur, E, NB);
  part2_k<<<NB, 256, 0, stream>>>(temp, offs, list, E, N, NB);
  node_gemm_k<<<(N + NG_ROWS - 1) / NG_ROWS, 256, 0, stream>>>(x, Wn, bn, h, N);
  gather_k<<<(N + 3) / 4, 256, 0, stream>>>(list, offs, deg, h, attr, We, be, out, N);
}